// Round 3
// baseline (657.673 us; speedup 1.0000x reference)
//
#include <hip/hip_runtime.h>

// ELBO for the chromatin "Decoding" model — round 3.
// vs round 2:
//  * cuts kernel restructured: 16-lane group per cut, 2 components per lane,
//    gene weight columns in 128 VGPRs (no LDS in the inner loop — round 2 was
//    LDS-return-bus bound at ~96 cyc/cut). Shuffle butterfly (d=1,2,4,8) for
//    the 32-component sums.
//  * scatter writes an 8B payload {x, (n_d<<16)|gix} so cuts streams
//    contiguously (round 2 did 3x random 4B gathers per cut -> 208MB FETCH).

#define TPB 256
#define HALF_LOG_2PI 0.9189385332046727f

// 256-thread block reduction; valid in thread 0 only.
static __device__ __forceinline__ float block_reduce(float v) {
  #pragma unroll
  for (int off = 32; off > 0; off >>= 1) v += __shfl_down(v, off, 64);
  __shared__ float wsum[4];
  if ((threadIdx.x & 63) == 0) wsum[threadIdx.x >> 6] = v;
  __syncthreads();
  return (threadIdx.x == 0) ? (wsum[0] + wsum[1] + wsum[2] + wsum[3]) : 0.f;
}

// ---------------- A: gene params ----------------
__global__ __launch_bounds__(TPB) void gene_params_kernel(
    const int* __restrict__ genes_oi,
    const float* __restrict__ loc_w, const float* __restrict__ scale_w,
    const float* __restrict__ logit_w,
    float4* __restrict__ gp, int G) {
  int idx = blockIdx.x * TPB + threadIdx.x;       // over G*32
  if (idx >= G * 32) return;
  int g = idx >> 5, c = idx & 31;
  long long gene = genes_oi[g];
  float lv = loc_w[gene * 32 + c];
  float loc = 1.f / (1.f + __expf(-lv));
  float sc = 1e-5f + __expf(scale_w[gene * 32 + c]);
  gp[idx] = make_float4(loc, 1.f / sc, -__logf(sc) - HALF_LOG_2PI, logit_w[gene * 32 + c]);
}

// ---------------- S1: histogram of cuts over g_d ----------------
__global__ __launch_bounds__(TPB) void bin_hist_kernel(
    const int* __restrict__ cxg, unsigned* __restrict__ binCnt, int K, unsigned G) {
  int k = blockIdx.x * TPB + threadIdx.x;
  if (k >= K) return;
  unsigned ix = (unsigned)cxg[k];
  atomicAdd(&binCnt[ix % G], 1u);
}

// ---------------- S2: exclusive scan over G bins (single block) ----------------
__global__ __launch_bounds__(TPB) void scan_kernel(
    const unsigned* __restrict__ cnt, unsigned* __restrict__ offs,
    unsigned* __restrict__ cur, int G, int K) {
  __shared__ unsigned tmp[TPB];
  __shared__ unsigned base;
  if (threadIdx.x == 0) base = 0;
  __syncthreads();
  for (int c0 = 0; c0 < G; c0 += TPB) {
    int i = c0 + threadIdx.x;
    unsigned v = (i < G) ? cnt[i] : 0u;
    tmp[threadIdx.x] = v;
    __syncthreads();
    #pragma unroll
    for (int d = 1; d < TPB; d <<= 1) {
      unsigned t = (threadIdx.x >= (unsigned)d) ? tmp[threadIdx.x - d] : 0u;
      __syncthreads();
      tmp[threadIdx.x] += t;
      __syncthreads();
    }
    unsigned excl = tmp[threadIdx.x] - v + base;
    if (i < G) { offs[i] = excl; cur[i] = excl; }
    __syncthreads();
    if (threadIdx.x == TPB - 1) base = excl + v;
    __syncthreads();
  }
  if (threadIdx.x == 0) offs[G] = (unsigned)K;
}

// ---------------- S3: scatter per-cut payload into gene-sorted order ---------
__global__ __launch_bounds__(TPB) void scatter_kernel(
    const int* __restrict__ cxg, const float* __restrict__ xc,
    const int* __restrict__ gix, unsigned* __restrict__ cur,
    float2* __restrict__ pl, int K, unsigned G) {
  int k = blockIdx.x * TPB + threadIdx.x;
  if (k >= K) return;
  unsigned ix = (unsigned)cxg[k];
  unsigned g_d = ix % G;
  unsigned n_d = ix / G;
  unsigned pos = atomicAdd(&cur[g_d], 1u);
  pl[pos] = make_float2(xc[k], __uint_as_float((n_d << 16) | (unsigned)gix[k]));
}

// ---------------- C: fragment-count histogram ----------------
__global__ __launch_bounds__(TPB) void hist_kernel(
    const int* __restrict__ lix, unsigned* __restrict__ counts, int F, long long NG) {
  int i = blockIdx.x * TPB + threadIdx.x;
  if (i >= F) return;
  long long v = lix[i];
  if (v >= 0 && v < NG) atomicAdd(&counts[v], 1u);
}

// ---------------- D: cuts, lane-parallel components ----------------
// block = gene. 16-lane group per cut (4 cuts/wave); lane owns comps {cc, cc+16}
// with W columns in 128 VGPRs. Inner loop: global broadcast float4 latent reads,
// FMA, 2 exps, 4-step shuffle butterfly. No LDS in the loop.
__global__ __launch_bounds__(TPB, 2) void cuts_kernel_v3(
    const float2* __restrict__ pl, const float* __restrict__ latent,
    const int* __restrict__ genes_oi, const float* __restrict__ logit_weight,
    const float4* __restrict__ gp, const unsigned* __restrict__ offs,
    float* __restrict__ partials, int G) {
  const int g = blockIdx.x;
  const int lane = threadIdx.x & 63;
  const int wv = threadIdx.x >> 6;
  const int cc = lane & 15;
  const int grp = lane >> 4;          // cut-in-quad 0..3

  __shared__ __align__(16) float Wl[2048];
  {
    long long gene = genes_oi[g];
    const float4* W4 = (const float4*)(logit_weight + gene * 2048);
    float4* S4 = (float4*)Wl;
    for (int t = threadIdx.x; t < 512; t += TPB) S4[t] = W4[t];
  }
  __syncthreads();

  // W columns cc and cc+16 into registers (broadcast LDS reads, conflict-free)
  float w0[64], w1[64];
  #pragma unroll
  for (int l = 0; l < 64; l++) {
    w0[l] = Wl[l * 32 + cc];
    w1[l] = Wl[l * 32 + cc + 16];
  }

  const unsigned start = offs[g], end = offs[g + 1];
  float lm = 0.f;
  for (unsigned k0 = start + wv * 4; k0 < end; k0 += 16) {
    unsigned kk = k0 + grp;
    bool valid = kk < end;
    float2 p = pl[valid ? kk : start];
    float x = p.x;
    unsigned u = __float_as_uint(p.y);
    unsigned n_d = u >> 16, gi = u & 0xffffu;
    const float4* latr = (const float4*)(latent + (size_t)n_d * 64);
    float acc0 = 0.f, acc1 = 0.f;
    #pragma unroll
    for (int i = 0; i < 16; i++) {
      float4 lv = latr[i];
      acc0 = fmaf(lv.x, w0[4 * i + 0], acc0); acc1 = fmaf(lv.x, w1[4 * i + 0], acc1);
      acc0 = fmaf(lv.y, w0[4 * i + 1], acc0); acc1 = fmaf(lv.y, w1[4 * i + 1], acc1);
      acc0 = fmaf(lv.z, w0[4 * i + 2], acc0); acc1 = fmaf(lv.z, w1[4 * i + 2], acc1);
      acc0 = fmaf(lv.w, w0[4 * i + 3], acc0); acc1 = fmaf(lv.w, w1[4 * i + 3], acc1);
    }
    const float4* gpr = gp + (size_t)gi * 32;
    float4 q0 = gpr[cc], q1 = gpr[cc + 16];
    float t0 = q0.w + acc0, t1 = q1.w + acc1;
    float z0 = (x - q0.x) * q0.y, z1 = (x - q1.x) * q1.y;
    float u0 = t0 + fmaf(-0.5f * z0, z0, q0.z);
    float u1 = t1 + fmaf(-0.5f * z1, z1, q1.z);
    float e1 = __expf(u0) + __expf(u1);
    float e2 = __expf(t0) + __expf(t1);
    #pragma unroll
    for (int d = 1; d < 16; d <<= 1) {
      e1 += __shfl_xor(e1, d, 64);
      e2 += __shfl_xor(e2, d, 64);
    }
    if (valid && cc == 0) lm += __logf(e1) - __logf(e2);
  }
  float bs = block_reduce(lm);
  if (threadIdx.x == 0) partials[blockIdx.x] = bs;
}

// ---------------- E: Poisson fragment counts ----------------
__global__ __launch_bounds__(TPB) void pois_kernel(
    const float* __restrict__ latent, const int* __restrict__ genes_oi,
    const int* __restrict__ cells_oi,
    const float* __restrict__ rho_weight, const float* __restrict__ rho_bias,
    const float* __restrict__ libsize,
    const unsigned* __restrict__ counts,
    float* __restrict__ partials, int N, int G) {
  int g = blockIdx.x * TPB + threadIdx.x;
  int n0 = blockIdx.y * 8;
  float sum = 0.f;
  if (g < G) {
    long long gene = genes_oi[g];
    const float4* rw = (const float4*)(rho_weight + gene * 64);
    float rho[8];
    #pragma unroll
    for (int j = 0; j < 8; j++) rho[j] = 0.f;
    #pragma unroll
    for (int l4 = 0; l4 < 16; l4++) {
      float4 w = rw[l4];
      #pragma unroll
      for (int j = 0; j < 8; j++) {
        int n = n0 + j;
        if (n < N) {
          float4 lv = *(const float4*)(latent + (size_t)n * 64 + l4 * 4);
          rho[j] += w.x * lv.x + w.y * lv.y + w.z * lv.z + w.w * lv.w;
        }
      }
    }
    float rb = rho_bias[gene];
    #pragma unroll
    for (int j = 0; j < 8; j++) {
      int n = n0 + j;
      if (n >= N) break;
      float lib = libsize[cells_oi[n]];
      float fe = rb * __expf(rho[j]) * lib;
      unsigned cnt = counts[(size_t)n * G + g];
      float term = -fe;
      if (cnt) {
        float lf = 0.f;
        for (unsigned q = 2; q <= cnt; q++) lf += __logf((float)q);
        term += (float)cnt * __logf(fe) - lf;
      }
      sum += term;
    }
  }
  float bs = block_reduce(sum);
  if (threadIdx.x == 0) partials[blockIdx.y * gridDim.x + blockIdx.x] = bs;
}

// ---------------- F: finalize ----------------
__global__ __launch_bounds__(TPB) void finalize_kernel(
    const float* __restrict__ p1, int n1,
    const float* __restrict__ p2, int n2, float* __restrict__ out) {
  float s = 0.f;
  for (int i = threadIdx.x; i < n1; i += TPB) s += p1[i];
  for (int i = threadIdx.x; i < n2; i += TPB) s += p2[i];
  float bs = block_reduce(s);
  if (threadIdx.x == 0) out[0] = -bs;
}

extern "C" void kernel_launch(void* const* d_in, const int* in_sizes, int n_in,
                              void* d_out, int out_size, void* d_ws, size_t ws_size,
                              hipStream_t stream) {
  const int*   lix          = (const int*)d_in[0];
  const float* xc           = (const float*)d_in[1];
  const float* latent       = (const float*)d_in[2];
  const int*   genes_oi     = (const int*)d_in[3];
  const int*   cells_oi     = (const int*)d_in[4];
  const int*   cxg          = (const int*)d_in[5];
  const int*   gix          = (const int*)d_in[6];
  const float* loc_w        = (const float*)d_in[9];
  const float* scale_w      = (const float*)d_in[10];
  const float* logit_w      = (const float*)d_in[11];
  const float* logit_weight = (const float*)d_in[12];
  const float* rho_weight   = (const float*)d_in[13];
  const float* rho_bias     = (const float*)d_in[14];
  const float* libsize      = (const float*)d_in[15];
  float* out = (float*)d_out;

  const int F = in_sizes[0];
  const int K = in_sizes[1];
  const int N = in_sizes[2] / 64;
  const int G = in_sizes[3];
  const long long NG = (long long)N * G;

  const int gpx = (G + TPB - 1) / TPB;
  const int npy = (N + 7) / 8;
  const int npb = gpx * npy;

  size_t off = 0;
  auto alloc = [&](size_t bytes) {
    size_t o = off;
    off = (off + bytes + 255) & ~(size_t)255;
    return o;
  };
  size_t counts_off = alloc((size_t)NG * 4);
  size_t gp_off     = alloc((size_t)G * 32 * 16);
  size_t bin_off    = alloc((size_t)G * 4);
  size_t offs_off   = alloc((size_t)(G + 1) * 4);
  size_t cur_off    = alloc((size_t)G * 4);
  size_t pl_off     = alloc((size_t)K * 8);
  size_t p1_off     = alloc((size_t)G * 4);
  size_t p2_off     = alloc((size_t)npb * 4);
  (void)ws_size;  // ~19 MB needed

  char* ws = (char*)d_ws;
  unsigned* counts = (unsigned*)(ws + counts_off);
  float4* gp       = (float4*)(ws + gp_off);
  unsigned* binCnt = (unsigned*)(ws + bin_off);
  unsigned* offs   = (unsigned*)(ws + offs_off);
  unsigned* cur    = (unsigned*)(ws + cur_off);
  float2* pl       = (float2*)(ws + pl_off);
  float* p1        = (float*)(ws + p1_off);
  float* p2        = (float*)(ws + p2_off);

  hipMemsetAsync(counts, 0, (size_t)NG * 4, stream);
  hipMemsetAsync(binCnt, 0, (size_t)G * 4, stream);

  gene_params_kernel<<<(G * 32 + TPB - 1) / TPB, TPB, 0, stream>>>(
      genes_oi, loc_w, scale_w, logit_w, gp, G);
  bin_hist_kernel<<<(K + TPB - 1) / TPB, TPB, 0, stream>>>(cxg, binCnt, K, (unsigned)G);
  scan_kernel<<<1, TPB, 0, stream>>>(binCnt, offs, cur, G, K);
  scatter_kernel<<<(K + TPB - 1) / TPB, TPB, 0, stream>>>(cxg, xc, gix, cur, pl, K, (unsigned)G);
  hist_kernel<<<(F + TPB - 1) / TPB, TPB, 0, stream>>>(lix, counts, F, NG);
  cuts_kernel_v3<<<G, TPB, 0, stream>>>(pl, latent, genes_oi, logit_weight, gp,
                                        offs, p1, G);
  dim3 pgrid(gpx, npy);
  pois_kernel<<<pgrid, TPB, 0, stream>>>(latent, genes_oi, cells_oi, rho_weight,
                                         rho_bias, libsize, counts, p2, N, G);
  finalize_kernel<<<1, TPB, 0, stream>>>(p1, G, p2, npb, out);
}